// Round 1
// baseline (1107.994 us; speedup 1.0000x reference)
//
#include <hip/hip_runtime.h>
#include <math.h>

// Problem constants (from reference setup_inputs)
constexpr int kN = 32768;   // nodes
constexpr int kE = 262144;  // edges
constexpr int kD = 256;     // hidden
constexpr int kH = 4;       // heads
constexpr int kC = 64;      // head dim
constexpr int kG = 32;      // graphs
constexpr float kScale = 0.125f;  // 1/sqrt(64)
constexpr float kEps = 1e-5f;

// ---------------------------------------------------------------- sort by dst
__global__ __launch_bounds__(256) void hist_kernel(const int* __restrict__ ei,
                                                   int* __restrict__ counts) {
  int e = blockIdx.x * 256 + threadIdx.x;
  atomicAdd(&counts[ei[kE + e]], 1);
}

__global__ __launch_bounds__(1024) void scan_kernel(const int* __restrict__ counts,
                                                    int* __restrict__ row_start,
                                                    int* __restrict__ cursor) {
  __shared__ int wsums[16];
  int t = threadIdx.x;
  int base_i = t * 32;
  int loc[32];
  int run = 0;
#pragma unroll
  for (int j = 0; j < 32; ++j) { loc[j] = run; run += counts[base_i + j]; }
  int incl = run;
  int lane = t & 63;
#pragma unroll
  for (int d = 1; d < 64; d <<= 1) {
    int v = __shfl_up(incl, d, 64);
    if (lane >= d) incl += v;
  }
  if (lane == 63) wsums[t >> 6] = incl;
  __syncthreads();
  if (t == 0) {
    int acc = 0;
    for (int w = 0; w < 16; ++w) { int tmp = wsums[w]; wsums[w] = acc; acc += tmp; }
  }
  __syncthreads();
  int base = wsums[t >> 6] + (incl - run);
#pragma unroll
  for (int j = 0; j < 32; ++j) {
    int v = base + loc[j];
    row_start[base_i + j] = v;
    cursor[base_i + j] = v;
  }
  if (t == 0) row_start[kN] = kE;
}

__global__ __launch_bounds__(256) void scatter_kernel(const int* __restrict__ ei,
                                                      int* __restrict__ cursor,
                                                      int* __restrict__ perm) {
  int e = blockIdx.x * 256 + threadIdx.x;
  int d = ei[kE + e];
  int pos = atomicAdd(&cursor[d], 1);
  perm[pos] = e;
}

// ---------------------------------------------------------------- encoder
__global__ __launch_bounds__(256) void enc_kernel(const float* __restrict__ X,
                                                  const float* __restrict__ encW,
                                                  const float* __restrict__ encb,
                                                  float* __restrict__ Hb) {
  int idx = blockIdx.x * 256 + threadIdx.x;  // over kN*64 float4
  int n = idx >> 6;
  int q = idx & 63;
  const float4* W4 = (const float4*)encW;
  float4 w0 = W4[q];
  float4 w1 = W4[64 + q];
  float4 bb = ((const float4*)encb)[q];
  float x0 = X[2 * n], x1 = X[2 * n + 1];
  float4 r;
  r.x = fmaf(x0, w0.x, fmaf(x1, w1.x, bb.x));
  r.y = fmaf(x0, w0.y, fmaf(x1, w1.y, bb.y));
  r.z = fmaf(x0, w0.z, fmaf(x1, w1.z, bb.z));
  r.w = fmaf(x0, w0.w, fmaf(x1, w1.w, bb.w));
  ((float4*)Hb)[idx] = r;
}

// ---------------------------------------------------------------- fused 4-GEMM
// Y = H @ W + b for W in {Wq,Wk,Wv,Wskip}; 128x128 tile, BK=16, 8x8/thread.
__global__ __launch_bounds__(256) void gemm4_kernel(
    const float* __restrict__ Hb,
    const float* __restrict__ Wq, const float* __restrict__ Wk,
    const float* __restrict__ Wv, const float* __restrict__ Ws,
    const float* __restrict__ bq, const float* __restrict__ bk,
    const float* __restrict__ bv, const float* __restrict__ bs,
    float* __restrict__ Oq, float* __restrict__ Ok,
    float* __restrict__ Ov, float* __restrict__ Os) {
  int cb = blockIdx.x;           // 0..7 : 2 col-blocks per weight matrix
  int m0 = blockIdx.y * 128;
  int wi = cb >> 1;
  int col0 = (cb & 1) * 128;
  const float* W; const float* bias; float* O;
  if (wi == 0)      { W = Wq; bias = bq; O = Oq; }
  else if (wi == 1) { W = Wk; bias = bk; O = Ok; }
  else if (wi == 2) { W = Wv; bias = bv; O = Ov; }
  else              { W = Ws; bias = bs; O = Os; }

  __shared__ float As[16][132];  // [k][m], padded
  __shared__ float Bs[16][128];  // [k][n]

  int tid = threadIdx.x;
  int tx = tid & 15;   // m block (8 rows each)
  int ty = tid >> 4;   // n block (8 cols each)

  float acc[8][8];
#pragma unroll
  for (int i = 0; i < 8; ++i)
#pragma unroll
    for (int j = 0; j < 8; ++j) acc[i][j] = 0.f;

  for (int kc = 0; kc < 256; kc += 16) {
#pragma unroll
    for (int r = 0; r < 2; ++r) {
      int fid = tid + r * 256;
      // A: 128 rows x 16 k  (512 float4)
      int m = fid >> 2;
      int kq = (fid & 3) * 4;
      float4 a = *(const float4*)&Hb[(size_t)(m0 + m) * 256 + kc + kq];
      As[kq + 0][m] = a.x;
      As[kq + 1][m] = a.y;
      As[kq + 2][m] = a.z;
      As[kq + 3][m] = a.w;
      // B: 16 k x 128 cols (512 float4)
      int kb = fid >> 5;
      int nq = (fid & 31) * 4;
      *(float4*)&Bs[kb][nq] = *(const float4*)&W[(size_t)(kc + kb) * 256 + col0 + nq];
    }
    __syncthreads();
#pragma unroll
    for (int k = 0; k < 16; ++k) {
      float a[8], b[8];
      *(float4*)&a[0] = *(const float4*)&As[k][tx * 8];
      *(float4*)&a[4] = *(const float4*)&As[k][tx * 8 + 4];
      *(float4*)&b[0] = *(const float4*)&Bs[k][ty * 8];
      *(float4*)&b[4] = *(const float4*)&Bs[k][ty * 8 + 4];
#pragma unroll
      for (int i = 0; i < 8; ++i)
#pragma unroll
        for (int j = 0; j < 8; ++j) acc[i][j] = fmaf(a[i], b[j], acc[i][j]);
    }
    __syncthreads();
  }

  float bvec[8];
#pragma unroll
  for (int j = 0; j < 8; ++j) bvec[j] = bias[col0 + ty * 8 + j];
#pragma unroll
  for (int i = 0; i < 8; ++i) {
    int row = m0 + tx * 8 + i;
    float4 o1, o2;
    o1.x = acc[i][0] + bvec[0]; o1.y = acc[i][1] + bvec[1];
    o1.z = acc[i][2] + bvec[2]; o1.w = acc[i][3] + bvec[3];
    o2.x = acc[i][4] + bvec[4]; o2.y = acc[i][5] + bvec[5];
    o2.z = acc[i][6] + bvec[6]; o2.w = acc[i][7] + bvec[7];
    *(float4*)&O[(size_t)row * 256 + col0 + ty * 8] = o1;
    *(float4*)&O[(size_t)row * 256 + col0 + ty * 8 + 4] = o2;
  }
}

// ---------------------------------------------------------------- attention
// one wave per destination node; online softmax over sorted incoming edges
__global__ __launch_bounds__(256) void attn_kernel(
    const float* __restrict__ Q, const float* __restrict__ K,
    const float* __restrict__ V, const float* __restrict__ eattr,
    const float* __restrict__ WeL, const int* __restrict__ ei,
    const int* __restrict__ perm, const int* __restrict__ row_start,
    float* __restrict__ Outp) {
  int wid = (blockIdx.x * 256 + threadIdx.x) >> 6;  // node id
  int lane = threadIdx.x & 63;
  float we[4], qv[4];
#pragma unroll
  for (int h = 0; h < 4; ++h) {
    we[h] = WeL[h * 64 + lane];
    qv[h] = Q[(size_t)wid * 256 + h * 64 + lane];
  }
  int s0 = row_start[wid], s1 = row_start[wid + 1];
  float m[4], lsum[4], acc[4];
#pragma unroll
  for (int h = 0; h < 4; ++h) { m[h] = -1e30f; lsum[h] = 0.f; acc[h] = 0.f; }
  for (int idx = s0; idx < s1; ++idx) {
    int e = perm[idx];
    int s = ei[e];
    float ea = eattr[e];
    float kv[4], vv[4];
#pragma unroll
    for (int h = 0; h < 4; ++h) {
      kv[h] = K[(size_t)s * 256 + h * 64 + lane] + ea * we[h];
      vv[h] = V[(size_t)s * 256 + h * 64 + lane] + ea * we[h];
    }
#pragma unroll
    for (int h = 0; h < 4; ++h) {
      float d = qv[h] * kv[h];
#pragma unroll
      for (int o = 32; o >= 1; o >>= 1) d += __shfl_xor(d, o, 64);
      float alpha = d * kScale;
      float mn = fmaxf(m[h], alpha);
      float co = __expf(m[h] - mn);
      float p = __expf(alpha - mn);
      lsum[h] = lsum[h] * co + p;
      acc[h] = acc[h] * co + p * vv[h];
      m[h] = mn;
    }
  }
#pragma unroll
  for (int h = 0; h < 4; ++h)
    Outp[(size_t)wid * 256 + h * 64 + lane] = lsum[h] > 0.f ? acc[h] / lsum[h] : 0.f;
}

// ---------------------------------------------------------------- beta gate + BN partials
__global__ __launch_bounds__(256) void beta_bn_kernel(
    const float* __restrict__ Att, const float* __restrict__ Xr,
    const float* __restrict__ Wb, float* __restrict__ Hb,
    float* __restrict__ bnsum, float* __restrict__ bnsq) {
  __shared__ float red[4][256];
  int tid = threadIdx.x;
  int w = tid >> 6;
  int lane = tid & 63;
  int gw = blockIdx.x * 4 + w;
  int nw = gridDim.x * 4;
  float wb1[4], wb2[4];
#pragma unroll
  for (int h = 0; h < 4; ++h) {
    float a = Wb[h * 64 + lane];
    float b = Wb[256 + h * 64 + lane];
    float c = Wb[512 + h * 64 + lane];
    wb1[h] = a + c;
    wb2[h] = b - c;
  }
  float cs[4] = {0.f, 0.f, 0.f, 0.f};
  float cq[4] = {0.f, 0.f, 0.f, 0.f};
  for (int i = gw; i < kN; i += nw) {
    float o[4], xr[4];
#pragma unroll
    for (int h = 0; h < 4; ++h) {
      o[h] = Att[(size_t)i * 256 + h * 64 + lane];
      xr[h] = Xr[(size_t)i * 256 + h * 64 + lane];
    }
    float t = 0.f;
#pragma unroll
    for (int h = 0; h < 4; ++h) t += o[h] * wb1[h] + xr[h] * wb2[h];
#pragma unroll
    for (int o2 = 32; o2 >= 1; o2 >>= 1) t += __shfl_xor(t, o2, 64);
    float beta = 1.f / (1.f + __expf(-t));
#pragma unroll
    for (int h = 0; h < 4; ++h) {
      float hn = beta * xr[h] + (1.f - beta) * o[h];
      Hb[(size_t)i * 256 + h * 64 + lane] = hn;
      cs[h] += hn;
      cq[h] += hn * hn;
    }
  }
#pragma unroll
  for (int h = 0; h < 4; ++h) red[w][h * 64 + lane] = cs[h];
  __syncthreads();
  if (tid < 256) {
    float s = red[0][tid] + red[1][tid] + red[2][tid] + red[3][tid];
    atomicAdd(&bnsum[tid], s);
  }
  __syncthreads();
#pragma unroll
  for (int h = 0; h < 4; ++h) red[w][h * 64 + lane] = cq[h];
  __syncthreads();
  if (tid < 256) {
    float s = red[0][tid] + red[1][tid] + red[2][tid] + red[3][tid];
    atomicAdd(&bnsq[tid], s);
  }
}

// ---------------------------------------------------------------- BN finalize + ELU
__global__ __launch_bounds__(256) void bn_elu_kernel(
    float* __restrict__ Hb, const float* __restrict__ bnsum,
    const float* __restrict__ bnsq, const float* __restrict__ gma,
    const float* __restrict__ bta) {
  int idx = blockIdx.x * 256 + threadIdx.x;  // over kN*64 float4
  int d4 = idx & 63;
  float4 hv = ((float4*)Hb)[idx];
  float4 s = ((const float4*)bnsum)[d4];
  float4 qq = ((const float4*)bnsq)[d4];
  float4 g = ((const float4*)gma)[d4];
  float4 b = ((const float4*)bta)[d4];
  const float inv_n = 1.f / (float)kN;
  auto f = [&](float h, float su, float sq, float ga, float be) {
    float mu = su * inv_n;
    float var = sq * inv_n - mu * mu;
    float y = ga * (h - mu) * rsqrtf(var + kEps) + be;
    return y > 0.f ? y : expm1f(y);
  };
  hv.x = f(hv.x, s.x, qq.x, g.x, b.x);
  hv.y = f(hv.y, s.y, qq.y, g.y, b.y);
  hv.z = f(hv.z, s.z, qq.z, g.z, b.z);
  hv.w = f(hv.w, s.w, qq.w, g.w, b.w);
  ((float4*)Hb)[idx] = hv;
}

// ---------------------------------------------------------------- readout
__global__ __launch_bounds__(256) void gate_kernel(const float* __restrict__ Hb,
                                                   const float* __restrict__ gW,
                                                   const float* __restrict__ gB,
                                                   float* __restrict__ gate) {
  int wid = (blockIdx.x * 256 + threadIdx.x) >> 6;
  int lane = threadIdx.x & 63;
  float t = 0.f;
#pragma unroll
  for (int h = 0; h < 4; ++h)
    t += Hb[(size_t)wid * 256 + h * 64 + lane] * gW[h * 64 + lane];
#pragma unroll
  for (int o = 32; o >= 1; o >>= 1) t += __shfl_xor(t, o, 64);
  if (lane == 0) gate[wid] = t + gB[0];
}

__device__ inline int lower_bound_dev(const int* a, int n, int key) {
  int lo = 0, hi = n;
  while (lo < hi) {
    int mid = (lo + hi) >> 1;
    if (a[mid] < key) lo = mid + 1; else hi = mid;
  }
  return lo;
}

__global__ __launch_bounds__(256) void pool_kernel(const float* __restrict__ Hb,
                                                   const float* __restrict__ gate,
                                                   const int* __restrict__ batch,
                                                   float* __restrict__ S,
                                                   float* __restrict__ den) {
  int g = blockIdx.x;
  int tid = threadIdx.x;
  int lo = lower_bound_dev(batch, kN, g);
  int hi = lower_bound_dev(batch, kN, g + 1);
  // block max of gate[lo..hi)
  float mx = -1e30f;
  for (int n = lo + tid; n < hi; n += 256) mx = fmaxf(mx, gate[n]);
  int lane = tid & 63, w = tid >> 6;
#pragma unroll
  for (int o = 32; o >= 1; o >>= 1) mx = fmaxf(mx, __shfl_xor(mx, o, 64));
  __shared__ float sm[4];
  if (lane == 0) sm[w] = mx;
  __syncthreads();
  mx = fmaxf(fmaxf(sm[0], sm[1]), fmaxf(sm[2], sm[3]));
  // accumulate weighted sum; thread tid owns column tid
  float sd = 0.f;
  float dn = 0.f;
  for (int n = lo; n < hi; ++n) {
    float a = __expf(gate[n] - mx);
    dn += a;
    sd += a * Hb[(size_t)n * 256 + tid];
  }
  S[g * 256 + tid] = sd;
  if (tid == 0) den[g] = dn;
}

__global__ __launch_bounds__(64) void final_kernel(const float* __restrict__ S,
                                                   const float* __restrict__ den,
                                                   const float* __restrict__ dW,
                                                   const float* __restrict__ dB,
                                                   const float* __restrict__ oB,
                                                   float* __restrict__ out) {
  int g = blockIdx.x;
  int lane = threadIdx.x;
  float t = 0.f;
#pragma unroll
  for (int c = 0; c < 4; ++c)
    t += S[g * 256 + c * 64 + lane] * dW[c * 64 + lane];
#pragma unroll
  for (int o = 32; o >= 1; o >>= 1) t += __shfl_xor(t, o, 64);
  if (lane == 0) {
    float d = den[g];
    out[g] = (d > 0.f ? t / d : 0.f) + dB[0] + oB[0];
  }
}

// ---------------------------------------------------------------- launch
extern "C" void kernel_launch(void* const* d_in, const int* in_sizes, int n_in,
                              void* d_out, int out_size, void* d_ws, size_t ws_size,
                              hipStream_t stream) {
  const float* x     = (const float*)d_in[0];
  const int*   ei    = (const int*)d_in[1];
  const float* eattr = (const float*)d_in[2];
  const int*   batch = (const int*)d_in[3];
  const float* encW  = (const float*)d_in[4];
  const float* encb  = (const float*)d_in[5];
  const float* Wq    = (const float*)d_in[6];
  const float* bq    = (const float*)d_in[7];
  const float* Wk    = (const float*)d_in[8];
  const float* bk    = (const float*)d_in[9];
  const float* Wv    = (const float*)d_in[10];
  const float* bv    = (const float*)d_in[11];
  const float* We    = (const float*)d_in[12];
  const float* Wsk   = (const float*)d_in[13];
  const float* bsk   = (const float*)d_in[14];
  const float* Wb    = (const float*)d_in[15];
  const float* bng   = (const float*)d_in[16];
  const float* bnb   = (const float*)d_in[17];
  const float* gW    = (const float*)d_in[18];
  const float* gB    = (const float*)d_in[19];
  const float* dW    = (const float*)d_in[20];
  const float* dB    = (const float*)d_in[21];
  const float* oB    = (const float*)d_in[22];
  float* out = (float*)d_out;

  char* base = (char*)d_ws;
  auto alloc = [&](size_t bytes) -> void* {
    void* p = (void*)base;
    base += (bytes + 255) & ~(size_t)255;
    return p;
  };
  float* hbuf   = (float*)alloc((size_t)kN * kD * 4);
  float* qbuf   = (float*)alloc((size_t)kN * kD * 4);
  float* kbuf   = (float*)alloc((size_t)kN * kD * 4);
  float* vbuf   = (float*)alloc((size_t)kN * kD * 4);
  float* xrbuf  = (float*)alloc((size_t)kN * kD * 4);
  float* attbuf = (float*)alloc((size_t)kN * kD * 4);
  float* gatebuf = (float*)alloc((size_t)kN * 4);
  int* rowst  = (int*)alloc((size_t)(kN + 1) * 4);
  int* cursor = (int*)alloc((size_t)kN * 4);
  int* counts = (int*)alloc((size_t)kN * 4);
  int* perm   = (int*)alloc((size_t)kE * 4);
  float* bnsum = (float*)alloc(2048);  // 256 sum + 256 sumsq contiguous
  float* bnsq = bnsum + 256;
  float* Sbuf = (float*)alloc((size_t)kG * kD * 4);
  float* den  = (float*)alloc((size_t)kG * 4);

  // edge sort by dst
  hipMemsetAsync(counts, 0, (size_t)kN * 4, stream);
  hist_kernel<<<kE / 256, 256, 0, stream>>>(ei, counts);
  scan_kernel<<<1, 1024, 0, stream>>>(counts, rowst, cursor);
  scatter_kernel<<<kE / 256, 256, 0, stream>>>(ei, cursor, perm);

  // encoder
  enc_kernel<<<kN * 64 / 256, 256, 0, stream>>>(x, encW, encb, hbuf);

  for (int l = 0; l < 2; ++l) {
    size_t wo = (size_t)l * kD * kD;
    size_t bo = (size_t)l * kD;
    gemm4_kernel<<<dim3(8, kN / 128), 256, 0, stream>>>(
        hbuf, Wq + wo, Wk + wo, Wv + wo, Wsk + wo,
        bq + bo, bk + bo, bv + bo, bsk + bo,
        qbuf, kbuf, vbuf, xrbuf);
    attn_kernel<<<kN / 4, 256, 0, stream>>>(qbuf, kbuf, vbuf, eattr,
                                            We + bo, ei, perm, rowst, attbuf);
    hipMemsetAsync(bnsum, 0, 2048, stream);
    beta_bn_kernel<<<256, 256, 0, stream>>>(attbuf, xrbuf, Wb + (size_t)l * 768,
                                            hbuf, bnsum, bnsq);
    bn_elu_kernel<<<kN * 64 / 256, 256, 0, stream>>>(hbuf, bnsum, bnsq,
                                                     bng + bo, bnb + bo);
  }

  // readout
  gate_kernel<<<kN / 4, 256, 0, stream>>>(hbuf, gW, gB, gatebuf);
  pool_kernel<<<kG, 256, 0, stream>>>(hbuf, gatebuf, batch, Sbuf, den);
  final_kernel<<<kG, 64, 0, stream>>>(Sbuf, den, dW, dB, oB, out);
}

// Round 2
// 848.777 us; speedup vs baseline: 1.3054x; 1.3054x over previous
//
#include <hip/hip_runtime.h>
#include <math.h>

// Problem constants (from reference setup_inputs)
constexpr int kN = 32768;   // nodes
constexpr int kE = 262144;  // edges
constexpr int kD = 256;     // hidden
constexpr int kH = 4;       // heads
constexpr int kC = 64;      // head dim
constexpr int kG = 32;      // graphs
constexpr float kScale = 0.125f;  // 1/sqrt(64)
constexpr float kEps = 1e-5f;

// ---------------------------------------------------------------- sort by dst
__global__ __launch_bounds__(256) void hist_kernel(const int* __restrict__ ei,
                                                   int* __restrict__ counts) {
  int e = blockIdx.x * 256 + threadIdx.x;
  atomicAdd(&counts[ei[kE + e]], 1);
}

__global__ __launch_bounds__(1024) void scan_kernel(const int* __restrict__ counts,
                                                    int* __restrict__ row_start,
                                                    int* __restrict__ cursor) {
  __shared__ int wsums[16];
  int t = threadIdx.x;
  int base_i = t * 32;
  int loc[32];
  int run = 0;
#pragma unroll
  for (int j = 0; j < 32; ++j) { loc[j] = run; run += counts[base_i + j]; }
  int incl = run;
  int lane = t & 63;
#pragma unroll
  for (int d = 1; d < 64; d <<= 1) {
    int v = __shfl_up(incl, d, 64);
    if (lane >= d) incl += v;
  }
  if (lane == 63) wsums[t >> 6] = incl;
  __syncthreads();
  if (t == 0) {
    int acc = 0;
    for (int w = 0; w < 16; ++w) { int tmp = wsums[w]; wsums[w] = acc; acc += tmp; }
  }
  __syncthreads();
  int base = wsums[t >> 6] + (incl - run);
#pragma unroll
  for (int j = 0; j < 32; ++j) {
    int v = base + loc[j];
    row_start[base_i + j] = v;
    cursor[base_i + j] = v;
  }
  if (t == 0) row_start[kN] = kE;
}

__global__ __launch_bounds__(256) void scatter_kernel(const int* __restrict__ ei,
                                                      int* __restrict__ cursor,
                                                      int* __restrict__ perm) {
  int e = blockIdx.x * 256 + threadIdx.x;
  int d = ei[kE + e];
  int pos = atomicAdd(&cursor[d], 1);
  perm[pos] = e;
}

// ---------------------------------------------------------------- encoder
__global__ __launch_bounds__(256) void enc_kernel(const float* __restrict__ X,
                                                  const float* __restrict__ encW,
                                                  const float* __restrict__ encb,
                                                  float* __restrict__ Hb) {
  int idx = blockIdx.x * 256 + threadIdx.x;  // over kN*64 float4
  int n = idx >> 6;
  int q = idx & 63;
  const float4* W4 = (const float4*)encW;
  float4 w0 = W4[q];
  float4 w1 = W4[64 + q];
  float4 bb = ((const float4*)encb)[q];
  float x0 = X[2 * n], x1 = X[2 * n + 1];
  float4 r;
  r.x = fmaf(x0, w0.x, fmaf(x1, w1.x, bb.x));
  r.y = fmaf(x0, w0.y, fmaf(x1, w1.y, bb.y));
  r.z = fmaf(x0, w0.z, fmaf(x1, w1.z, bb.z));
  r.w = fmaf(x0, w0.w, fmaf(x1, w1.w, bb.w));
  ((float4*)Hb)[idx] = r;
}

// ---------------------------------------------------------------- fused 4-GEMM
// Y = H @ W + b for W in {Wq,Wk,Wv,Wskip}; 128x128 tile, BK=16, 8x8/thread.
__global__ __launch_bounds__(256) void gemm4_kernel(
    const float* __restrict__ Hb,
    const float* __restrict__ Wq, const float* __restrict__ Wk,
    const float* __restrict__ Wv, const float* __restrict__ Ws,
    const float* __restrict__ bq, const float* __restrict__ bk,
    const float* __restrict__ bv, const float* __restrict__ bs,
    float* __restrict__ Oq, float* __restrict__ Ok,
    float* __restrict__ Ov, float* __restrict__ Os) {
  int cb = blockIdx.x;           // 0..7 : 2 col-blocks per weight matrix
  int m0 = blockIdx.y * 128;
  int wi = cb >> 1;
  int col0 = (cb & 1) * 128;
  const float* W; const float* bias; float* O;
  if (wi == 0)      { W = Wq; bias = bq; O = Oq; }
  else if (wi == 1) { W = Wk; bias = bk; O = Ok; }
  else if (wi == 2) { W = Wv; bias = bv; O = Ov; }
  else              { W = Ws; bias = bs; O = Os; }

  __shared__ float As[16][132];  // [k][m], padded
  __shared__ float Bs[16][128];  // [k][n]

  int tid = threadIdx.x;
  int tx = tid & 15;   // m block (8 rows each)
  int ty = tid >> 4;   // n block (8 cols each)

  float acc[8][8];
#pragma unroll
  for (int i = 0; i < 8; ++i)
#pragma unroll
    for (int j = 0; j < 8; ++j) acc[i][j] = 0.f;

  for (int kc = 0; kc < 256; kc += 16) {
#pragma unroll
    for (int r = 0; r < 2; ++r) {
      int fid = tid + r * 256;
      // A: 128 rows x 16 k  (512 float4)
      int m = fid >> 2;
      int kq = (fid & 3) * 4;
      float4 a = *(const float4*)&Hb[(size_t)(m0 + m) * 256 + kc + kq];
      As[kq + 0][m] = a.x;
      As[kq + 1][m] = a.y;
      As[kq + 2][m] = a.z;
      As[kq + 3][m] = a.w;
      // B: 16 k x 128 cols (512 float4)
      int kb = fid >> 5;
      int nq = (fid & 31) * 4;
      *(float4*)&Bs[kb][nq] = *(const float4*)&W[(size_t)(kc + kb) * 256 + col0 + nq];
    }
    __syncthreads();
#pragma unroll
    for (int k = 0; k < 16; ++k) {
      float a[8], b[8];
      *(float4*)&a[0] = *(const float4*)&As[k][tx * 8];
      *(float4*)&a[4] = *(const float4*)&As[k][tx * 8 + 4];
      *(float4*)&b[0] = *(const float4*)&Bs[k][ty * 8];
      *(float4*)&b[4] = *(const float4*)&Bs[k][ty * 8 + 4];
#pragma unroll
      for (int i = 0; i < 8; ++i)
#pragma unroll
        for (int j = 0; j < 8; ++j) acc[i][j] = fmaf(a[i], b[j], acc[i][j]);
    }
    __syncthreads();
  }

  float bvec[8];
#pragma unroll
  for (int j = 0; j < 8; ++j) bvec[j] = bias[col0 + ty * 8 + j];
#pragma unroll
  for (int i = 0; i < 8; ++i) {
    int row = m0 + tx * 8 + i;
    float4 o1, o2;
    o1.x = acc[i][0] + bvec[0]; o1.y = acc[i][1] + bvec[1];
    o1.z = acc[i][2] + bvec[2]; o1.w = acc[i][3] + bvec[3];
    o2.x = acc[i][4] + bvec[4]; o2.y = acc[i][5] + bvec[5];
    o2.z = acc[i][6] + bvec[6]; o2.w = acc[i][7] + bvec[7];
    *(float4*)&O[(size_t)row * 256 + col0 + ty * 8] = o1;
    *(float4*)&O[(size_t)row * 256 + col0 + ty * 8 + 4] = o2;
  }
}

// ---------------------------------------------------------------- attention
// one wave per destination node; online softmax over sorted incoming edges
__global__ __launch_bounds__(256) void attn_kernel(
    const float* __restrict__ Q, const float* __restrict__ K,
    const float* __restrict__ V, const float* __restrict__ eattr,
    const float* __restrict__ WeL, const int* __restrict__ ei,
    const int* __restrict__ perm, const int* __restrict__ row_start,
    float* __restrict__ Outp) {
  int wid = (blockIdx.x * 256 + threadIdx.x) >> 6;  // node id
  int lane = threadIdx.x & 63;
  float we[4], qv[4];
#pragma unroll
  for (int h = 0; h < 4; ++h) {
    we[h] = WeL[h * 64 + lane];
    qv[h] = Q[(size_t)wid * 256 + h * 64 + lane];
  }
  int s0 = row_start[wid], s1 = row_start[wid + 1];
  float m[4], lsum[4], acc[4];
#pragma unroll
  for (int h = 0; h < 4; ++h) { m[h] = -1e30f; lsum[h] = 0.f; acc[h] = 0.f; }
  for (int idx = s0; idx < s1; ++idx) {
    int e = perm[idx];
    int s = ei[e];
    float ea = eattr[e];
    float kv[4], vv[4];
#pragma unroll
    for (int h = 0; h < 4; ++h) {
      kv[h] = K[(size_t)s * 256 + h * 64 + lane] + ea * we[h];
      vv[h] = V[(size_t)s * 256 + h * 64 + lane] + ea * we[h];
    }
#pragma unroll
    for (int h = 0; h < 4; ++h) {
      float d = qv[h] * kv[h];
#pragma unroll
      for (int o = 32; o >= 1; o >>= 1) d += __shfl_xor(d, o, 64);
      float alpha = d * kScale;
      float mn = fmaxf(m[h], alpha);
      float co = __expf(m[h] - mn);
      float p = __expf(alpha - mn);
      lsum[h] = lsum[h] * co + p;
      acc[h] = acc[h] * co + p * vv[h];
      m[h] = mn;
    }
  }
#pragma unroll
  for (int h = 0; h < 4; ++h)
    Outp[(size_t)wid * 256 + h * 64 + lane] = lsum[h] > 0.f ? acc[h] / lsum[h] : 0.f;
}

// ---------------------------------------------------------------- beta gate + BN partials
__global__ __launch_bounds__(256) void beta_bn_kernel(
    const float* __restrict__ Att, const float* __restrict__ Xr,
    const float* __restrict__ Wb, float* __restrict__ Hb,
    float* __restrict__ bnsum, float* __restrict__ bnsq) {
  __shared__ float red[4][256];
  int tid = threadIdx.x;
  int w = tid >> 6;
  int lane = tid & 63;
  int gw = blockIdx.x * 4 + w;
  int nw = gridDim.x * 4;
  float wb1[4], wb2[4];
#pragma unroll
  for (int h = 0; h < 4; ++h) {
    float a = Wb[h * 64 + lane];
    float b = Wb[256 + h * 64 + lane];
    float c = Wb[512 + h * 64 + lane];
    wb1[h] = a + c;
    wb2[h] = b - c;
  }
  float cs[4] = {0.f, 0.f, 0.f, 0.f};
  float cq[4] = {0.f, 0.f, 0.f, 0.f};
  for (int i = gw; i < kN; i += nw) {
    float o[4], xr[4];
#pragma unroll
    for (int h = 0; h < 4; ++h) {
      o[h] = Att[(size_t)i * 256 + h * 64 + lane];
      xr[h] = Xr[(size_t)i * 256 + h * 64 + lane];
    }
    float t = 0.f;
#pragma unroll
    for (int h = 0; h < 4; ++h) t += o[h] * wb1[h] + xr[h] * wb2[h];
#pragma unroll
    for (int o2 = 32; o2 >= 1; o2 >>= 1) t += __shfl_xor(t, o2, 64);
    float beta = 1.f / (1.f + __expf(-t));
#pragma unroll
    for (int h = 0; h < 4; ++h) {
      float hn = beta * xr[h] + (1.f - beta) * o[h];
      Hb[(size_t)i * 256 + h * 64 + lane] = hn;
      cs[h] += hn;
      cq[h] += hn * hn;
    }
  }
#pragma unroll
  for (int h = 0; h < 4; ++h) red[w][h * 64 + lane] = cs[h];
  __syncthreads();
  if (tid < 256) {
    float s = red[0][tid] + red[1][tid] + red[2][tid] + red[3][tid];
    atomicAdd(&bnsum[tid], s);
  }
  __syncthreads();
#pragma unroll
  for (int h = 0; h < 4; ++h) red[w][h * 64 + lane] = cq[h];
  __syncthreads();
  if (tid < 256) {
    float s = red[0][tid] + red[1][tid] + red[2][tid] + red[3][tid];
    atomicAdd(&bnsq[tid], s);
  }
}

// ---------------------------------------------------------------- BN finalize + ELU
__global__ __launch_bounds__(256) void bn_elu_kernel(
    float* __restrict__ Hb, const float* __restrict__ bnsum,
    const float* __restrict__ bnsq, const float* __restrict__ gma,
    const float* __restrict__ bta) {
  int idx = blockIdx.x * 256 + threadIdx.x;  // over kN*64 float4
  int d4 = idx & 63;
  float4 hv = ((float4*)Hb)[idx];
  float4 s = ((const float4*)bnsum)[d4];
  float4 qq = ((const float4*)bnsq)[d4];
  float4 g = ((const float4*)gma)[d4];
  float4 b = ((const float4*)bta)[d4];
  const float inv_n = 1.f / (float)kN;
  auto f = [&](float h, float su, float sq, float ga, float be) {
    float mu = su * inv_n;
    float var = sq * inv_n - mu * mu;
    float y = ga * (h - mu) * rsqrtf(var + kEps) + be;
    return y > 0.f ? y : expm1f(y);
  };
  hv.x = f(hv.x, s.x, qq.x, g.x, b.x);
  hv.y = f(hv.y, s.y, qq.y, g.y, b.y);
  hv.z = f(hv.z, s.z, qq.z, g.z, b.z);
  hv.w = f(hv.w, s.w, qq.w, g.w, b.w);
  ((float4*)Hb)[idx] = hv;
}

// ---------------------------------------------------------------- readout
// fused gate + decode scalar: gate[n] = h_n . gW + gB ; dec[n] = h_n . dW
__global__ __launch_bounds__(256) void gate_dec_kernel(const float* __restrict__ Hb,
                                                       const float* __restrict__ gW,
                                                       const float* __restrict__ gB,
                                                       const float* __restrict__ dW,
                                                       float* __restrict__ gate,
                                                       float* __restrict__ dec) {
  int wid = (blockIdx.x * 256 + threadIdx.x) >> 6;
  int lane = threadIdx.x & 63;
  float tg = 0.f, td = 0.f;
#pragma unroll
  for (int h = 0; h < 4; ++h) {
    float hv = Hb[(size_t)wid * 256 + h * 64 + lane];
    tg += hv * gW[h * 64 + lane];
    td += hv * dW[h * 64 + lane];
  }
#pragma unroll
  for (int o = 32; o >= 1; o >>= 1) {
    tg += __shfl_xor(tg, o, 64);
    td += __shfl_xor(td, o, 64);
  }
  if (lane == 0) {
    gate[wid] = tg + gB[0];
    dec[wid] = td;
  }
}

__device__ inline int lower_bound_dev(const int* a, int n, int key) {
  int lo = 0, hi = n;
  while (lo < hi) {
    int mid = (lo + hi) >> 1;
    if (a[mid] < key) lo = mid + 1; else hi = mid;
  }
  return lo;
}

// scalar segment-softmax pooling: out[g] = sum(a_n dec_n)/sum(a_n) + dB + oB
__global__ __launch_bounds__(256) void pool2_kernel(const float* __restrict__ gate,
                                                    const float* __restrict__ dec,
                                                    const int* __restrict__ batch,
                                                    const float* __restrict__ dB,
                                                    const float* __restrict__ oB,
                                                    float* __restrict__ out) {
  int g = blockIdx.x;
  int tid = threadIdx.x;
  int lane = tid & 63, w = tid >> 6;
  int lo = lower_bound_dev(batch, kN, g);
  int hi = lower_bound_dev(batch, kN, g + 1);
  float mx = -1e30f;
  for (int n = lo + tid; n < hi; n += 256) mx = fmaxf(mx, gate[n]);
#pragma unroll
  for (int o = 32; o >= 1; o >>= 1) mx = fmaxf(mx, __shfl_xor(mx, o, 64));
  __shared__ float sm[4];
  if (lane == 0) sm[w] = mx;
  __syncthreads();
  mx = fmaxf(fmaxf(sm[0], sm[1]), fmaxf(sm[2], sm[3]));
  float sn = 0.f, sd = 0.f;
  for (int n = lo + tid; n < hi; n += 256) {
    float a = __expf(gate[n] - mx);
    sn += a * dec[n];
    sd += a;
  }
#pragma unroll
  for (int o = 32; o >= 1; o >>= 1) {
    sn += __shfl_xor(sn, o, 64);
    sd += __shfl_xor(sd, o, 64);
  }
  __shared__ float s1[4], s2[4];
  if (lane == 0) { s1[w] = sn; s2[w] = sd; }
  __syncthreads();
  if (tid == 0) {
    float num = s1[0] + s1[1] + s1[2] + s1[3];
    float den = s2[0] + s2[1] + s2[2] + s2[3];
    out[g] = (den > 0.f ? num / den : 0.f) + dB[0] + oB[0];
  }
}

// ---------------------------------------------------------------- launch
extern "C" void kernel_launch(void* const* d_in, const int* in_sizes, int n_in,
                              void* d_out, int out_size, void* d_ws, size_t ws_size,
                              hipStream_t stream) {
  const float* x     = (const float*)d_in[0];
  const int*   ei    = (const int*)d_in[1];
  const float* eattr = (const float*)d_in[2];
  const int*   batch = (const int*)d_in[3];
  const float* encW  = (const float*)d_in[4];
  const float* encb  = (const float*)d_in[5];
  const float* Wq    = (const float*)d_in[6];
  const float* bq    = (const float*)d_in[7];
  const float* Wk    = (const float*)d_in[8];
  const float* bk    = (const float*)d_in[9];
  const float* Wv    = (const float*)d_in[10];
  const float* bv    = (const float*)d_in[11];
  const float* We    = (const float*)d_in[12];
  const float* Wsk   = (const float*)d_in[13];
  const float* bsk   = (const float*)d_in[14];
  const float* Wb    = (const float*)d_in[15];
  const float* bng   = (const float*)d_in[16];
  const float* bnb   = (const float*)d_in[17];
  const float* gW    = (const float*)d_in[18];
  const float* gB    = (const float*)d_in[19];
  const float* dW    = (const float*)d_in[20];
  const float* dB    = (const float*)d_in[21];
  const float* oB    = (const float*)d_in[22];
  float* out = (float*)d_out;

  char* base = (char*)d_ws;
  auto alloc = [&](size_t bytes) -> void* {
    void* p = (void*)base;
    base += (bytes + 255) & ~(size_t)255;
    return p;
  };
  float* hbuf   = (float*)alloc((size_t)kN * kD * 4);
  float* qbuf   = (float*)alloc((size_t)kN * kD * 4);
  float* kbuf   = (float*)alloc((size_t)kN * kD * 4);
  float* vbuf   = (float*)alloc((size_t)kN * kD * 4);
  float* xrbuf  = (float*)alloc((size_t)kN * kD * 4);
  float* attbuf = (float*)alloc((size_t)kN * kD * 4);
  float* gatebuf = (float*)alloc((size_t)kN * 4);
  float* decbuf  = (float*)alloc((size_t)kN * 4);
  int* rowst  = (int*)alloc((size_t)(kN + 1) * 4);
  int* cursor = (int*)alloc((size_t)kN * 4);
  int* counts = (int*)alloc((size_t)kN * 4);
  int* perm   = (int*)alloc((size_t)kE * 4);
  float* bnsum = (float*)alloc(2048);  // 256 sum + 256 sumsq contiguous
  float* bnsq = bnsum + 256;

  // edge sort by dst
  hipMemsetAsync(counts, 0, (size_t)kN * 4, stream);
  hist_kernel<<<kE / 256, 256, 0, stream>>>(ei, counts);
  scan_kernel<<<1, 1024, 0, stream>>>(counts, rowst, cursor);
  scatter_kernel<<<kE / 256, 256, 0, stream>>>(ei, cursor, perm);

  // encoder
  enc_kernel<<<kN * 64 / 256, 256, 0, stream>>>(x, encW, encb, hbuf);

  for (int l = 0; l < 2; ++l) {
    size_t wo = (size_t)l * kD * kD;
    size_t bo = (size_t)l * kD;
    gemm4_kernel<<<dim3(8, kN / 128), 256, 0, stream>>>(
        hbuf, Wq + wo, Wk + wo, Wv + wo, Wsk + wo,
        bq + bo, bk + bo, bv + bo, bsk + bo,
        qbuf, kbuf, vbuf, xrbuf);
    attn_kernel<<<kN / 4, 256, 0, stream>>>(qbuf, kbuf, vbuf, eattr,
                                            We + bo, ei, perm, rowst, attbuf);
    hipMemsetAsync(bnsum, 0, 2048, stream);
    beta_bn_kernel<<<256, 256, 0, stream>>>(attbuf, xrbuf, Wb + (size_t)l * 768,
                                            hbuf, bnsum, bnsq);
    bn_elu_kernel<<<kN * 64 / 256, 256, 0, stream>>>(hbuf, bnsum, bnsq,
                                                     bng + bo, bnb + bo);
  }

  // readout
  gate_dec_kernel<<<kN / 4, 256, 0, stream>>>(hbuf, gW, gB, dW, gatebuf, decbuf);
  pool2_kernel<<<kG, 256, 0, stream>>>(gatebuf, decbuf, batch, dB, oB, out);
}

// Round 3
// 549.033 us; speedup vs baseline: 2.0181x; 1.5459x over previous
//
#include <hip/hip_runtime.h>
#include <hip/hip_bf16.h>
#include <math.h>

// Problem constants (from reference setup_inputs)
constexpr int kN = 32768;   // nodes
constexpr int kE = 262144;  // edges
constexpr int kD = 256;     // hidden
constexpr int kH = 4;       // heads
constexpr int kC = 64;      // head dim
constexpr int kG = 32;      // graphs
constexpr float kScale = 0.125f;  // 1/sqrt(64)
constexpr float kEps = 1e-5f;

typedef __attribute__((ext_vector_type(8))) short short8;     // 8 bf16 = 4 VGPR
typedef __attribute__((ext_vector_type(4))) float floatx4;

__device__ inline unsigned short f2bf(float f) {
  union { __hip_bfloat16 b; unsigned short u; } cv;
  cv.b = __float2bfloat16(f);
  return cv.u;
}

__device__ inline void async_copy16(const void* g, void* l) {
  __builtin_amdgcn_global_load_lds(
      (const __attribute__((address_space(1))) void*)g,
      (__attribute__((address_space(3))) void*)l, 16, 0, 0);
}

// ---------------------------------------------------------------- sort by dst
__global__ __launch_bounds__(256) void hist_kernel(const int* __restrict__ ei,
                                                   int* __restrict__ counts) {
  int e = blockIdx.x * 256 + threadIdx.x;
  atomicAdd(&counts[ei[kE + e]], 1);
}

__global__ __launch_bounds__(1024) void scan_kernel(const int* __restrict__ counts,
                                                    int* __restrict__ row_start,
                                                    int* __restrict__ cursor) {
  __shared__ int wsums[16];
  int t = threadIdx.x;
  int base_i = t * 32;
  int loc[32];
  int run = 0;
#pragma unroll
  for (int j = 0; j < 32; ++j) { loc[j] = run; run += counts[base_i + j]; }
  int incl = run;
  int lane = t & 63;
#pragma unroll
  for (int d = 1; d < 64; d <<= 1) {
    int v = __shfl_up(incl, d, 64);
    if (lane >= d) incl += v;
  }
  if (lane == 63) wsums[t >> 6] = incl;
  __syncthreads();
  if (t == 0) {
    int acc = 0;
    for (int w = 0; w < 16; ++w) { int tmp = wsums[w]; wsums[w] = acc; acc += tmp; }
  }
  __syncthreads();
  int base = wsums[t >> 6] + (incl - run);
#pragma unroll
  for (int j = 0; j < 32; ++j) {
    int v = base + loc[j];
    row_start[base_i + j] = v;
    cursor[base_i + j] = v;
  }
  if (t == 0) row_start[kN] = kE;
}

__global__ __launch_bounds__(256) void scatter_kernel(const int* __restrict__ ei,
                                                      int* __restrict__ cursor,
                                                      int* __restrict__ perm) {
  int e = blockIdx.x * 256 + threadIdx.x;
  int d = ei[kE + e];
  int pos = atomicAdd(&cursor[d], 1);
  perm[pos] = e;
}

// ---------------------------------------------------------------- weight transpose + bf16
// Wt[slot][n][k] = W[slot][k][n] as bf16 ; slot = l*4 + {q,k,v,skip}
__global__ __launch_bounds__(256) void transpose_w_kernel(
    const float* __restrict__ Wq, const float* __restrict__ Wk,
    const float* __restrict__ Wv, const float* __restrict__ Ws,
    __hip_bfloat16* __restrict__ Wt) {
  __shared__ float T[32][33];
  int kt = blockIdx.x, nt = blockIdx.y, slot = blockIdx.z;
  int l = slot >> 2, mat = slot & 3;
  const float* src;
  if (mat == 0) src = Wq; else if (mat == 1) src = Wk;
  else if (mat == 2) src = Wv; else src = Ws;
  src += (size_t)l * 65536;
  int tid = threadIdx.x;
#pragma unroll
  for (int i = 0; i < 4; ++i) {
    int idx = tid + i * 256;
    int r = idx >> 5, c = idx & 31;
    T[r][c] = src[(size_t)(kt * 32 + r) * 256 + nt * 32 + c];
  }
  __syncthreads();
  __hip_bfloat16* dst = Wt + (size_t)slot * 65536;
#pragma unroll
  for (int i = 0; i < 4; ++i) {
    int idx = tid + i * 256;
    int r = idx >> 5, c = idx & 31;
    dst[(size_t)(nt * 32 + r) * 256 + kt * 32 + c] = __float2bfloat16(T[c][r]);
  }
}

// ---------------------------------------------------------------- encoder (+ bf16 copy)
__global__ __launch_bounds__(256) void enc_kernel(const float* __restrict__ X,
                                                  const float* __restrict__ encW,
                                                  const float* __restrict__ encb,
                                                  float* __restrict__ Hb,
                                                  __hip_bfloat16* __restrict__ H16) {
  int idx = blockIdx.x * 256 + threadIdx.x;  // over kN*64 float4
  int n = idx >> 6;
  int q = idx & 63;
  const float4* W4 = (const float4*)encW;
  float4 w0 = W4[q];
  float4 w1 = W4[64 + q];
  float4 bb = ((const float4*)encb)[q];
  float x0 = X[2 * n], x1 = X[2 * n + 1];
  float4 r;
  r.x = fmaf(x0, w0.x, fmaf(x1, w1.x, bb.x));
  r.y = fmaf(x0, w0.y, fmaf(x1, w1.y, bb.y));
  r.z = fmaf(x0, w0.z, fmaf(x1, w1.z, bb.z));
  r.w = fmaf(x0, w0.w, fmaf(x1, w1.w, bb.w));
  ((float4*)Hb)[idx] = r;
  ushort4 rb;
  rb.x = f2bf(r.x); rb.y = f2bf(r.y); rb.z = f2bf(r.z); rb.w = f2bf(r.w);
  ((ushort4*)H16)[idx] = rb;
}

// ---------------------------------------------------------------- fused 4-GEMM (bf16 MFMA)
// Y = H @ W + b for W in {Wq,Wk,Wv,Wskip}; H16 [N][256] bf16, Wt [slot][n][k] bf16.
// 128x128 tile per block, BK=32, 4 waves each 64x64 via 4x4 mfma_f32_16x16x32_bf16.
__global__ __launch_bounds__(256) void gemm4_mfma(
    const __hip_bfloat16* __restrict__ H16,
    const __hip_bfloat16* __restrict__ Wt,  // 4 slots for this layer
    const float* __restrict__ bq, const float* __restrict__ bk,
    const float* __restrict__ bv, const float* __restrict__ bs,
    float* __restrict__ Oq, float* __restrict__ Ok,
    float* __restrict__ Ov, float* __restrict__ Os) {
  int cb = blockIdx.x;           // 0..7 : (matrix, col-half)
  int m0 = blockIdx.y * 128;
  int wi = cb >> 1;
  int col0 = (cb & 1) * 128;
  const __hip_bfloat16* Wm = Wt + (size_t)wi * 65536;
  const float* bias; float* O;
  if (wi == 0)      { bias = bq; O = Oq; }
  else if (wi == 1) { bias = bk; O = Ok; }
  else if (wi == 2) { bias = bv; O = Ov; }
  else              { bias = bs; O = Os; }

  __shared__ __align__(16) __hip_bfloat16 As[128 * 32];  // [m][k] row-major
  __shared__ __align__(16) __hip_bfloat16 Bs[128 * 32];  // [n][k] row-major

  int tid = threadIdx.x;
  int w = tid >> 6, lane = tid & 63;
  int wm = w & 1, wn = w >> 1;

  floatx4 acc[4][4];
#pragma unroll
  for (int i = 0; i < 4; ++i)
#pragma unroll
    for (int j = 0; j < 4; ++j) acc[i][j] = (floatx4){0.f, 0.f, 0.f, 0.f};

  int srow = lane >> 2;          // 0..15 (staging row within 16-row segment)
  int schunk = (lane & 3) * 8;   // 0,8,16,24 (bf16 elements)
  int arow = lane & 15, aq = lane >> 4;

  for (int kc = 0; kc < 256; kc += 32) {
#pragma unroll
    for (int t = 0; t < 2; ++t) {
      int s = w * 2 + t;  // segment 0..7 (16 rows each)
      const __hip_bfloat16* gA =
          H16 + (size_t)(m0 + s * 16 + srow) * 256 + kc + schunk;
      async_copy16(gA, (void*)(As + s * 512));
      const __hip_bfloat16* gB =
          Wm + (size_t)(col0 + s * 16 + srow) * 256 + kc + schunk;
      async_copy16(gB, (void*)(Bs + s * 512));
    }
    __syncthreads();
    short8 af[4], bf[4];
#pragma unroll
    for (int mi = 0; mi < 4; ++mi)
      af[mi] = *(const short8*)&As[(wm * 64 + mi * 16 + arow) * 32 + aq * 8];
#pragma unroll
    for (int ni = 0; ni < 4; ++ni)
      bf[ni] = *(const short8*)&Bs[(wn * 64 + ni * 16 + arow) * 32 + aq * 8];
#pragma unroll
    for (int mi = 0; mi < 4; ++mi)
#pragma unroll
      for (int ni = 0; ni < 4; ++ni)
        acc[mi][ni] = __builtin_amdgcn_mfma_f32_16x16x32_bf16(
            af[mi], bf[ni], acc[mi][ni], 0, 0, 0);
    __syncthreads();
  }

  // epilogue: C/D layout col=lane&15, row=(lane>>4)*4+reg
  int col = lane & 15, rq = (lane >> 4) * 4;
#pragma unroll
  for (int ni = 0; ni < 4; ++ni) {
    int ccol = col0 + wn * 64 + ni * 16 + col;
    float bvv = bias[ccol];
#pragma unroll
    for (int mi = 0; mi < 4; ++mi) {
      int rbase = m0 + wm * 64 + mi * 16 + rq;
#pragma unroll
      for (int r = 0; r < 4; ++r)
        O[(size_t)(rbase + r) * 256 + ccol] = acc[mi][ni][r] + bvv;
    }
  }
}

// ---------------------------------------------------------------- attention
// one wave per destination node; online softmax over sorted incoming edges
__global__ __launch_bounds__(256) void attn_kernel(
    const float* __restrict__ Q, const float* __restrict__ K,
    const float* __restrict__ V, const float* __restrict__ eattr,
    const float* __restrict__ WeL, const int* __restrict__ ei,
    const int* __restrict__ perm, const int* __restrict__ row_start,
    float* __restrict__ Outp) {
  int wid = (blockIdx.x * 256 + threadIdx.x) >> 6;  // node id
  int lane = threadIdx.x & 63;
  float we[4], qv[4];
#pragma unroll
  for (int h = 0; h < 4; ++h) {
    we[h] = WeL[h * 64 + lane];
    qv[h] = Q[(size_t)wid * 256 + h * 64 + lane];
  }
  int s0 = row_start[wid], s1 = row_start[wid + 1];
  float m[4], lsum[4], acc[4];
#pragma unroll
  for (int h = 0; h < 4; ++h) { m[h] = -1e30f; lsum[h] = 0.f; acc[h] = 0.f; }
  for (int idx = s0; idx < s1; ++idx) {
    int e = perm[idx];
    int s = ei[e];
    float ea = eattr[e];
    float kv[4], vv[4];
#pragma unroll
    for (int h = 0; h < 4; ++h) {
      kv[h] = K[(size_t)s * 256 + h * 64 + lane] + ea * we[h];
      vv[h] = V[(size_t)s * 256 + h * 64 + lane] + ea * we[h];
    }
#pragma unroll
    for (int h = 0; h < 4; ++h) {
      float d = qv[h] * kv[h];
#pragma unroll
      for (int o = 32; o >= 1; o >>= 1) d += __shfl_xor(d, o, 64);
      float alpha = d * kScale;
      float mn = fmaxf(m[h], alpha);
      float co = __expf(m[h] - mn);
      float p = __expf(alpha - mn);
      lsum[h] = lsum[h] * co + p;
      acc[h] = acc[h] * co + p * vv[h];
      m[h] = mn;
    }
  }
#pragma unroll
  for (int h = 0; h < 4; ++h)
    Outp[(size_t)wid * 256 + h * 64 + lane] = lsum[h] > 0.f ? acc[h] / lsum[h] : 0.f;
}

// ---------------------------------------------------------------- beta gate + BN partials
__global__ __launch_bounds__(256) void beta_bn_kernel(
    const float* __restrict__ Att, const float* __restrict__ Xr,
    const float* __restrict__ Wb, float* __restrict__ Hb,
    float* __restrict__ bnsum, float* __restrict__ bnsq) {
  __shared__ float red[4][256];
  int tid = threadIdx.x;
  int w = tid >> 6;
  int lane = tid & 63;
  int gw = blockIdx.x * 4 + w;
  int nw = gridDim.x * 4;
  float wb1[4], wb2[4];
#pragma unroll
  for (int h = 0; h < 4; ++h) {
    float a = Wb[h * 64 + lane];
    float b = Wb[256 + h * 64 + lane];
    float c = Wb[512 + h * 64 + lane];
    wb1[h] = a + c;
    wb2[h] = b - c;
  }
  float cs[4] = {0.f, 0.f, 0.f, 0.f};
  float cq[4] = {0.f, 0.f, 0.f, 0.f};
  for (int i = gw; i < kN; i += nw) {
    float o[4], xr[4];
#pragma unroll
    for (int h = 0; h < 4; ++h) {
      o[h] = Att[(size_t)i * 256 + h * 64 + lane];
      xr[h] = Xr[(size_t)i * 256 + h * 64 + lane];
    }
    float t = 0.f;
#pragma unroll
    for (int h = 0; h < 4; ++h) t += o[h] * wb1[h] + xr[h] * wb2[h];
#pragma unroll
    for (int o2 = 32; o2 >= 1; o2 >>= 1) t += __shfl_xor(t, o2, 64);
    float beta = 1.f / (1.f + __expf(-t));
#pragma unroll
    for (int h = 0; h < 4; ++h) {
      float hn = beta * xr[h] + (1.f - beta) * o[h];
      Hb[(size_t)i * 256 + h * 64 + lane] = hn;
      cs[h] += hn;
      cq[h] += hn * hn;
    }
  }
#pragma unroll
  for (int h = 0; h < 4; ++h) red[w][h * 64 + lane] = cs[h];
  __syncthreads();
  if (tid < 256) {
    float s = red[0][tid] + red[1][tid] + red[2][tid] + red[3][tid];
    atomicAdd(&bnsum[tid], s);
  }
  __syncthreads();
#pragma unroll
  for (int h = 0; h < 4; ++h) red[w][h * 64 + lane] = cq[h];
  __syncthreads();
  if (tid < 256) {
    float s = red[0][tid] + red[1][tid] + red[2][tid] + red[3][tid];
    atomicAdd(&bnsq[tid], s);
  }
}

// ---------------------------------------------------------------- BN finalize + ELU (+ bf16 copy)
__global__ __launch_bounds__(256) void bn_elu_kernel(
    float* __restrict__ Hb, const float* __restrict__ bnsum,
    const float* __restrict__ bnsq, const float* __restrict__ gma,
    const float* __restrict__ bta, __hip_bfloat16* __restrict__ H16) {
  int idx = blockIdx.x * 256 + threadIdx.x;  // over kN*64 float4
  int d4 = idx & 63;
  float4 hv = ((float4*)Hb)[idx];
  float4 s = ((const float4*)bnsum)[d4];
  float4 qq = ((const float4*)bnsq)[d4];
  float4 g = ((const float4*)gma)[d4];
  float4 b = ((const float4*)bta)[d4];
  const float inv_n = 1.f / (float)kN;
  auto f = [&](float h, float su, float sq, float ga, float be) {
    float mu = su * inv_n;
    float var = sq * inv_n - mu * mu;
    float y = ga * (h - mu) * rsqrtf(var + kEps) + be;
    return y > 0.f ? y : expm1f(y);
  };
  hv.x = f(hv.x, s.x, qq.x, g.x, b.x);
  hv.y = f(hv.y, s.y, qq.y, g.y, b.y);
  hv.z = f(hv.z, s.z, qq.z, g.z, b.z);
  hv.w = f(hv.w, s.w, qq.w, g.w, b.w);
  ((float4*)Hb)[idx] = hv;
  ushort4 rb;
  rb.x = f2bf(hv.x); rb.y = f2bf(hv.y); rb.z = f2bf(hv.z); rb.w = f2bf(hv.w);
  ((ushort4*)H16)[idx] = rb;
}

// ---------------------------------------------------------------- readout
// fused gate + decode scalar: gate[n] = h_n . gW + gB ; dec[n] = h_n . dW
__global__ __launch_bounds__(256) void gate_dec_kernel(const float* __restrict__ Hb,
                                                       const float* __restrict__ gW,
                                                       const float* __restrict__ gB,
                                                       const float* __restrict__ dW,
                                                       float* __restrict__ gate,
                                                       float* __restrict__ dec) {
  int wid = (blockIdx.x * 256 + threadIdx.x) >> 6;
  int lane = threadIdx.x & 63;
  float tg = 0.f, td = 0.f;
#pragma unroll
  for (int h = 0; h < 4; ++h) {
    float hv = Hb[(size_t)wid * 256 + h * 64 + lane];
    tg += hv * gW[h * 64 + lane];
    td += hv * dW[h * 64 + lane];
  }
#pragma unroll
  for (int o = 32; o >= 1; o >>= 1) {
    tg += __shfl_xor(tg, o, 64);
    td += __shfl_xor(td, o, 64);
  }
  if (lane == 0) {
    gate[wid] = tg + gB[0];
    dec[wid] = td;
  }
}

__device__ inline int lower_bound_dev(const int* a, int n, int key) {
  int lo = 0, hi = n;
  while (lo < hi) {
    int mid = (lo + hi) >> 1;
    if (a[mid] < key) lo = mid + 1; else hi = mid;
  }
  return lo;
}

// scalar segment-softmax pooling: out[g] = sum(a_n dec_n)/sum(a_n) + dB + oB
__global__ __launch_bounds__(256) void pool2_kernel(const float* __restrict__ gate,
                                                    const float* __restrict__ dec,
                                                    const int* __restrict__ batch,
                                                    const float* __restrict__ dB,
                                                    const float* __restrict__ oB,
                                                    float* __restrict__ out) {
  int g = blockIdx.x;
  int tid = threadIdx.x;
  int lane = tid & 63, w = tid >> 6;
  int lo = lower_bound_dev(batch, kN, g);
  int hi = lower_bound_dev(batch, kN, g + 1);
  float mx = -1e30f;
  for (int n = lo + tid; n < hi; n += 256) mx = fmaxf(mx, gate[n]);
#pragma unroll
  for (int o = 32; o >= 1; o >>= 1) mx = fmaxf(mx, __shfl_xor(mx, o, 64));
  __shared__ float sm[4];
  if (lane == 0) sm[w] = mx;
  __syncthreads();
  mx = fmaxf(fmaxf(sm[0], sm[1]), fmaxf(sm[2], sm[3]));
  float sn = 0.f, sd = 0.f;
  for (int n = lo + tid; n < hi; n += 256) {
    float a = __expf(gate[n] - mx);
    sn += a * dec[n];
    sd += a;
  }
#pragma unroll
  for (int o = 32; o >= 1; o >>= 1) {
    sn += __shfl_xor(sn, o, 64);
    sd += __shfl_xor(sd, o, 64);
  }
  __shared__ float s1[4], s2[4];
  if (lane == 0) { s1[w] = sn; s2[w] = sd; }
  __syncthreads();
  if (tid == 0) {
    float num = s1[0] + s1[1] + s1[2] + s1[3];
    float den = s2[0] + s2[1] + s2[2] + s2[3];
    out[g] = (den > 0.f ? num / den : 0.f) + dB[0] + oB[0];
  }
}

// ---------------------------------------------------------------- launch
extern "C" void kernel_launch(void* const* d_in, const int* in_sizes, int n_in,
                              void* d_out, int out_size, void* d_ws, size_t ws_size,
                              hipStream_t stream) {
  const float* x     = (const float*)d_in[0];
  const int*   ei    = (const int*)d_in[1];
  const float* eattr = (const float*)d_in[2];
  const int*   batch = (const int*)d_in[3];
  const float* encW  = (const float*)d_in[4];
  const float* encb  = (const float*)d_in[5];
  const float* Wq    = (const float*)d_in[6];
  const float* bq    = (const float*)d_in[7];
  const float* Wk    = (const float*)d_in[8];
  const float* bk    = (const float*)d_in[9];
  const float* Wv    = (const float*)d_in[10];
  const float* bv    = (const float*)d_in[11];
  const float* We    = (const float*)d_in[12];
  const float* Wsk   = (const float*)d_in[13];
  const float* bsk   = (const float*)d_in[14];
  const float* Wb    = (const float*)d_in[15];
  const float* bng   = (const float*)d_in[16];
  const float* bnb   = (const float*)d_in[17];
  const float* gW    = (const float*)d_in[18];
  const float* gB    = (const float*)d_in[19];
  const float* dW    = (const float*)d_in[20];
  const float* dB    = (const float*)d_in[21];
  const float* oB    = (const float*)d_in[22];
  float* out = (float*)d_out;

  char* base = (char*)d_ws;
  auto alloc = [&](size_t bytes) -> void* {
    void* p = (void*)base;
    base += (bytes + 255) & ~(size_t)255;
    return p;
  };
  float* hbuf   = (float*)alloc((size_t)kN * kD * 4);
  float* qbuf   = (float*)alloc((size_t)kN * kD * 4);
  float* kbuf   = (float*)alloc((size_t)kN * kD * 4);
  float* vbuf   = (float*)alloc((size_t)kN * kD * 4);
  float* xrbuf  = (float*)alloc((size_t)kN * kD * 4);
  float* attbuf = (float*)alloc((size_t)kN * kD * 4);
  __hip_bfloat16* h16 = (__hip_bfloat16*)alloc((size_t)kN * kD * 2);
  __hip_bfloat16* wt16 = (__hip_bfloat16*)alloc((size_t)8 * 65536 * 2);
  float* gatebuf = (float*)alloc((size_t)kN * 4);
  float* decbuf  = (float*)alloc((size_t)kN * 4);
  int* rowst  = (int*)alloc((size_t)(kN + 1) * 4);
  int* cursor = (int*)alloc((size_t)kN * 4);
  int* counts = (int*)alloc((size_t)kN * 4);
  int* perm   = (int*)alloc((size_t)kE * 4);
  float* bnsum = (float*)alloc(2048);  // 256 sum + 256 sumsq contiguous
  float* bnsq = bnsum + 256;

  // edge sort by dst
  hipMemsetAsync(counts, 0, (size_t)kN * 4, stream);
  hist_kernel<<<kE / 256, 256, 0, stream>>>(ei, counts);
  scan_kernel<<<1, 1024, 0, stream>>>(counts, rowst, cursor);
  scatter_kernel<<<kE / 256, 256, 0, stream>>>(ei, cursor, perm);

  // weights -> transposed bf16 (once)
  transpose_w_kernel<<<dim3(8, 8, 8), 256, 0, stream>>>(Wq, Wk, Wv, Wsk, wt16);

  // encoder (+ bf16 h)
  enc_kernel<<<kN * 64 / 256, 256, 0, stream>>>(x, encW, encb, hbuf, h16);

  for (int l = 0; l < 2; ++l) {
    size_t bo = (size_t)l * kD;
    gemm4_mfma<<<dim3(8, kN / 128), 256, 0, stream>>>(
        h16, wt16 + (size_t)l * 4 * 65536,
        bq + bo, bk + bo, bv + bo, bsk + bo,
        qbuf, kbuf, vbuf, xrbuf);
    attn_kernel<<<kN / 4, 256, 0, stream>>>(qbuf, kbuf, vbuf, eattr,
                                            We + bo, ei, perm, rowst, attbuf);
    hipMemsetAsync(bnsum, 0, 2048, stream);
    beta_bn_kernel<<<256, 256, 0, stream>>>(attbuf, xrbuf, Wb + (size_t)l * 768,
                                            hbuf, bnsum, bnsq);
    bn_elu_kernel<<<kN * 64 / 256, 256, 0, stream>>>(hbuf, bnsum, bnsq,
                                                     bng + bo, bnb + bo, h16);
  }

  // readout
  gate_dec_kernel<<<kN / 4, 256, 0, stream>>>(hbuf, gW, gB, dW, gatebuf, decbuf);
  pool2_kernel<<<kG, 256, 0, stream>>>(gatebuf, decbuf, batch, dB, oB, out);
}

// Round 4
// 468.002 us; speedup vs baseline: 2.3675x; 1.1731x over previous
//
#include <hip/hip_runtime.h>
#include <hip/hip_bf16.h>
#include <math.h>

// Problem constants (from reference setup_inputs)
constexpr int kN = 32768;   // nodes
constexpr int kE = 262144;  // edges
constexpr int kD = 256;     // hidden
constexpr int kH = 4;       // heads
constexpr int kC = 64;      // head dim
constexpr int kG = 32;      // graphs
constexpr float kScale = 0.125f;  // 1/sqrt(64)
constexpr float kEps = 1e-5f;

typedef __attribute__((ext_vector_type(8))) short short8;     // 8 bf16 = 4 VGPR
typedef __attribute__((ext_vector_type(4))) float floatx4;

__device__ inline unsigned short f2bf(float f) {
  union { __hip_bfloat16 b; unsigned short u; } cv;
  cv.b = __float2bfloat16(f);
  return cv.u;
}

__device__ inline float bf2f(unsigned int u16) {
  union { float f; unsigned int i; } c;
  c.i = u16 << 16;
  return c.f;
}

__device__ inline void async_copy16(const void* g, void* l) {
  __builtin_amdgcn_global_load_lds(
      (const __attribute__((address_space(1))) void*)g,
      (__attribute__((address_space(3))) void*)l, 16, 0, 0);
}

// ---------------------------------------------------------------- sort by dst
__global__ __launch_bounds__(256) void hist_kernel(const int* __restrict__ ei,
                                                   int* __restrict__ counts) {
  int e = blockIdx.x * 256 + threadIdx.x;
  atomicAdd(&counts[ei[kE + e]], 1);
}

__global__ __launch_bounds__(1024) void scan_kernel(const int* __restrict__ counts,
                                                    int* __restrict__ row_start,
                                                    int* __restrict__ cursor) {
  __shared__ int wsums[16];
  int t = threadIdx.x;
  int base_i = t * 32;
  int loc[32];
  int run = 0;
#pragma unroll
  for (int j = 0; j < 32; ++j) { loc[j] = run; run += counts[base_i + j]; }
  int incl = run;
  int lane = t & 63;
#pragma unroll
  for (int d = 1; d < 64; d <<= 1) {
    int v = __shfl_up(incl, d, 64);
    if (lane >= d) incl += v;
  }
  if (lane == 63) wsums[t >> 6] = incl;
  __syncthreads();
  if (t == 0) {
    int acc = 0;
    for (int w = 0; w < 16; ++w) { int tmp = wsums[w]; wsums[w] = acc; acc += tmp; }
  }
  __syncthreads();
  int base = wsums[t >> 6] + (incl - run);
#pragma unroll
  for (int j = 0; j < 32; ++j) {
    int v = base + loc[j];
    row_start[base_i + j] = v;
    cursor[base_i + j] = v;
  }
  if (t == 0) row_start[kN] = kE;
}

__global__ __launch_bounds__(256) void scatter_kernel(const int* __restrict__ ei,
                                                      int* __restrict__ cursor,
                                                      int* __restrict__ perm) {
  int e = blockIdx.x * 256 + threadIdx.x;
  int d = ei[kE + e];
  int pos = atomicAdd(&cursor[d], 1);
  perm[pos] = e;
}

// ---------------------------------------------------------------- weight transpose + bf16
// Wt[slot][n][k] = W[slot][k][n] as bf16 ; slot = l*4 + {q,k,v,skip}
__global__ __launch_bounds__(256) void transpose_w_kernel(
    const float* __restrict__ Wq, const float* __restrict__ Wk,
    const float* __restrict__ Wv, const float* __restrict__ Ws,
    __hip_bfloat16* __restrict__ Wt) {
  __shared__ float T[32][33];
  int kt = blockIdx.x, nt = blockIdx.y, slot = blockIdx.z;
  int l = slot >> 2, mat = slot & 3;
  const float* src;
  if (mat == 0) src = Wq; else if (mat == 1) src = Wk;
  else if (mat == 2) src = Wv; else src = Ws;
  src += (size_t)l * 65536;
  int tid = threadIdx.x;
#pragma unroll
  for (int i = 0; i < 4; ++i) {
    int idx = tid + i * 256;
    int r = idx >> 5, c = idx & 31;
    T[r][c] = src[(size_t)(kt * 32 + r) * 256 + nt * 32 + c];
  }
  __syncthreads();
  __hip_bfloat16* dst = Wt + (size_t)slot * 65536;
#pragma unroll
  for (int i = 0; i < 4; ++i) {
    int idx = tid + i * 256;
    int r = idx >> 5, c = idx & 31;
    dst[(size_t)(nt * 32 + r) * 256 + kt * 32 + c] = __float2bfloat16(T[c][r]);
  }
}

// ---------------------------------------------------------------- encoder (bf16 only)
__global__ __launch_bounds__(256) void enc_kernel(const float* __restrict__ X,
                                                  const float* __restrict__ encW,
                                                  const float* __restrict__ encb,
                                                  __hip_bfloat16* __restrict__ H16) {
  int idx = blockIdx.x * 256 + threadIdx.x;  // over kN*64 float4
  int n = idx >> 6;
  int q = idx & 63;
  const float4* W4 = (const float4*)encW;
  float4 w0 = W4[q];
  float4 w1 = W4[64 + q];
  float4 bb = ((const float4*)encb)[q];
  float x0 = X[2 * n], x1 = X[2 * n + 1];
  float4 r;
  r.x = fmaf(x0, w0.x, fmaf(x1, w1.x, bb.x));
  r.y = fmaf(x0, w0.y, fmaf(x1, w1.y, bb.y));
  r.z = fmaf(x0, w0.z, fmaf(x1, w1.z, bb.z));
  r.w = fmaf(x0, w0.w, fmaf(x1, w1.w, bb.w));
  ushort4 rb;
  rb.x = f2bf(r.x); rb.y = f2bf(r.y); rb.z = f2bf(r.z); rb.w = f2bf(r.w);
  ((ushort4*)H16)[idx] = rb;
}

// ---------------------------------------------------------------- fused 4-GEMM (bf16 MFMA)
// Y = H @ W + b.  Q,Xr -> fp32 buffers; K,V -> interleaved bf16 KV buffer:
// KV[node] is 1024B: chunk c (c=0..63) = { k[4c..4c+3] bf16, v[4c..4c+3] bf16 }.
__global__ __launch_bounds__(256) void gemm4_mfma(
    const __hip_bfloat16* __restrict__ H16,
    const __hip_bfloat16* __restrict__ Wt,  // 4 slots for this layer
    const float* __restrict__ bq, const float* __restrict__ bk,
    const float* __restrict__ bv, const float* __restrict__ bs,
    float* __restrict__ Oq, unsigned short* __restrict__ KV,
    float* __restrict__ Os) {
  int cb = blockIdx.x;           // 0..7 : (matrix, col-half)
  int m0 = blockIdx.y * 128;
  int wi = cb >> 1;
  int col0 = (cb & 1) * 128;
  const __hip_bfloat16* Wm = Wt + (size_t)wi * 65536;
  const float* bias;
  if (wi == 0)      bias = bq;
  else if (wi == 1) bias = bk;
  else if (wi == 2) bias = bv;
  else              bias = bs;

  __shared__ __align__(16) __hip_bfloat16 As[128 * 32];  // [m][k] row-major
  __shared__ __align__(16) __hip_bfloat16 Bs[128 * 32];  // [n][k] row-major

  int tid = threadIdx.x;
  int w = tid >> 6, lane = tid & 63;
  int wm = w & 1, wn = w >> 1;

  floatx4 acc[4][4];
#pragma unroll
  for (int i = 0; i < 4; ++i)
#pragma unroll
    for (int j = 0; j < 4; ++j) acc[i][j] = (floatx4){0.f, 0.f, 0.f, 0.f};

  int srow = lane >> 2;          // 0..15 (staging row within 16-row segment)
  int schunk = (lane & 3) * 8;   // 0,8,16,24 (bf16 elements)
  int arow = lane & 15, aq = lane >> 4;

  for (int kc = 0; kc < 256; kc += 32) {
#pragma unroll
    for (int t = 0; t < 2; ++t) {
      int s = w * 2 + t;  // segment 0..7 (16 rows each)
      const __hip_bfloat16* gA =
          H16 + (size_t)(m0 + s * 16 + srow) * 256 + kc + schunk;
      async_copy16(gA, (void*)(As + s * 512));
      const __hip_bfloat16* gB =
          Wm + (size_t)(col0 + s * 16 + srow) * 256 + kc + schunk;
      async_copy16(gB, (void*)(Bs + s * 512));
    }
    __syncthreads();
    short8 af[4], bf[4];
#pragma unroll
    for (int mi = 0; mi < 4; ++mi)
      af[mi] = *(const short8*)&As[(wm * 64 + mi * 16 + arow) * 32 + aq * 8];
#pragma unroll
    for (int ni = 0; ni < 4; ++ni)
      bf[ni] = *(const short8*)&Bs[(wn * 64 + ni * 16 + arow) * 32 + aq * 8];
#pragma unroll
    for (int mi = 0; mi < 4; ++mi)
#pragma unroll
      for (int ni = 0; ni < 4; ++ni)
        acc[mi][ni] = __builtin_amdgcn_mfma_f32_16x16x32_bf16(
            af[mi], bf[ni], acc[mi][ni], 0, 0, 0);
    __syncthreads();
  }

  // epilogue: C/D layout col=lane&15, row=(lane>>4)*4+reg
  int col = lane & 15, rq = (lane >> 4) * 4;
  if (wi == 0 || wi == 3) {
    float* O = (wi == 0) ? Oq : Os;
#pragma unroll
    for (int ni = 0; ni < 4; ++ni) {
      int ccol = col0 + wn * 64 + ni * 16 + col;
      float bvv = bias[ccol];
#pragma unroll
      for (int mi = 0; mi < 4; ++mi) {
        int rbase = m0 + wm * 64 + mi * 16 + rq;
#pragma unroll
        for (int r = 0; r < 4; ++r)
          O[(size_t)(rbase + r) * 256 + ccol] = acc[mi][ni][r] + bvv;
      }
    }
  } else {
    int off = (wi == 2) ? 4 : 0;  // K in first half of chunk, V in second
#pragma unroll
    for (int ni = 0; ni < 4; ++ni) {
      int ccol = col0 + wn * 64 + ni * 16 + col;
      float bvv = bias[ccol];
      size_t cofs = (size_t)(ccol >> 2) * 8 + off + (ccol & 3);
#pragma unroll
      for (int mi = 0; mi < 4; ++mi) {
        int rbase = m0 + wm * 64 + mi * 16 + rq;
#pragma unroll
        for (int r = 0; r < 4; ++r)
          KV[(size_t)(rbase + r) * 512 + cofs] = f2bf(acc[mi][ni][r] + bvv);
      }
    }
  }
}

// ---------------------------------------------------------------- attention
// one wave per destination node. Lane L owns channels 4L..4L+3 (all of head
// L>>4): one uint4 load per edge fetches its k-quad + v-quad; dot reduces
// over a 16-lane butterfly; softmax state is per head-group, no broadcast.
__global__ __launch_bounds__(256) void attn_kernel(
    const float* __restrict__ Q, const uint4* __restrict__ KV,
    const float* __restrict__ eattr, const float* __restrict__ WeL,
    const int* __restrict__ ei, const int* __restrict__ perm,
    const int* __restrict__ row_start, float* __restrict__ Outp) {
  int wid = (blockIdx.x * 256 + threadIdx.x) >> 6;  // node id
  int lane = threadIdx.x & 63;
  float4 q4 = ((const float4*)(Q + (size_t)wid * 256))[lane];
  float4 we4 = ((const float4*)WeL)[lane];
  int s0 = row_start[wid], s1 = row_start[wid + 1];
  float m = -1e30f, lsum = 0.f;
  float4 acc = {0.f, 0.f, 0.f, 0.f};

  float ea = 0.f;
  uint4 raw = {0, 0, 0, 0};
  if (s0 < s1) {
    int e = perm[s0];
    int s = ei[e];
    ea = eattr[e];
    raw = KV[(size_t)s * 64 + lane];
  }
  for (int idx = s0; idx < s1; ++idx) {
    // prefetch next edge while processing current
    float ea2 = 0.f;
    uint4 raw2 = {0, 0, 0, 0};
    if (idx + 1 < s1) {
      int e2 = perm[idx + 1];
      int s2 = ei[e2];
      ea2 = eattr[e2];
      raw2 = KV[(size_t)s2 * 64 + lane];
    }
    float k0 = bf2f(raw.x & 0xffffu), k1 = bf2f(raw.x >> 16);
    float k2 = bf2f(raw.y & 0xffffu), k3 = bf2f(raw.y >> 16);
    float v0 = bf2f(raw.z & 0xffffu), v1 = bf2f(raw.z >> 16);
    float v2 = bf2f(raw.w & 0xffffu), v3 = bf2f(raw.w >> 16);
    float kv0 = fmaf(ea, we4.x, k0), kv1 = fmaf(ea, we4.y, k1);
    float kv2 = fmaf(ea, we4.z, k2), kv3 = fmaf(ea, we4.w, k3);
    float vv0 = fmaf(ea, we4.x, v0), vv1 = fmaf(ea, we4.y, v1);
    float vv2 = fmaf(ea, we4.z, v2), vv3 = fmaf(ea, we4.w, v3);
    float d = q4.x * kv0 + q4.y * kv1 + q4.z * kv2 + q4.w * kv3;
    // reduce within the 16-lane head group (bits 0..3)
    d += __shfl_xor(d, 1, 64);
    d += __shfl_xor(d, 2, 64);
    d += __shfl_xor(d, 4, 64);
    d += __shfl_xor(d, 8, 64);
    float alpha = d * kScale;
    float mn = fmaxf(m, alpha);
    float co = __expf(m - mn);
    float p = __expf(alpha - mn);
    lsum = lsum * co + p;
    acc.x = acc.x * co + p * vv0;
    acc.y = acc.y * co + p * vv1;
    acc.z = acc.z * co + p * vv2;
    acc.w = acc.w * co + p * vv3;
    m = mn;
    ea = ea2;
    raw = raw2;
  }
  float inv = lsum > 0.f ? 1.f / lsum : 0.f;
  float4 o;
  o.x = acc.x * inv; o.y = acc.y * inv; o.z = acc.z * inv; o.w = acc.w * inv;
  ((float4*)(Outp + (size_t)wid * 256))[lane] = o;
}

// ---------------------------------------------------------------- beta gate + BN partials
__global__ __launch_bounds__(256) void beta_bn_kernel(
    const float* __restrict__ Att, const float* __restrict__ Xr,
    const float* __restrict__ Wb, float* __restrict__ Hb,
    float* __restrict__ bnsum, float* __restrict__ bnsq) {
  __shared__ float red[4][256];
  int tid = threadIdx.x;
  int w = tid >> 6;
  int lane = tid & 63;
  int gw = blockIdx.x * 4 + w;
  int nw = gridDim.x * 4;
  float wb1[4], wb2[4];
#pragma unroll
  for (int h = 0; h < 4; ++h) {
    float a = Wb[h * 64 + lane];
    float b = Wb[256 + h * 64 + lane];
    float c = Wb[512 + h * 64 + lane];
    wb1[h] = a + c;
    wb2[h] = b - c;
  }
  float cs[4] = {0.f, 0.f, 0.f, 0.f};
  float cq[4] = {0.f, 0.f, 0.f, 0.f};
  for (int i = gw; i < kN; i += nw) {
    float o[4], xr[4];
#pragma unroll
    for (int h = 0; h < 4; ++h) {
      o[h] = Att[(size_t)i * 256 + h * 64 + lane];
      xr[h] = Xr[(size_t)i * 256 + h * 64 + lane];
    }
    float t = 0.f;
#pragma unroll
    for (int h = 0; h < 4; ++h) t += o[h] * wb1[h] + xr[h] * wb2[h];
#pragma unroll
    for (int o2 = 32; o2 >= 1; o2 >>= 1) t += __shfl_xor(t, o2, 64);
    float beta = 1.f / (1.f + __expf(-t));
#pragma unroll
    for (int h = 0; h < 4; ++h) {
      float hn = beta * xr[h] + (1.f - beta) * o[h];
      Hb[(size_t)i * 256 + h * 64 + lane] = hn;
      cs[h] += hn;
      cq[h] += hn * hn;
    }
  }
#pragma unroll
  for (int h = 0; h < 4; ++h) red[w][h * 64 + lane] = cs[h];
  __syncthreads();
  if (tid < 256) {
    float s = red[0][tid] + red[1][tid] + red[2][tid] + red[3][tid];
    atomicAdd(&bnsum[tid], s);
  }
  __syncthreads();
#pragma unroll
  for (int h = 0; h < 4; ++h) red[w][h * 64 + lane] = cq[h];
  __syncthreads();
  if (tid < 256) {
    float s = red[0][tid] + red[1][tid] + red[2][tid] + red[3][tid];
    atomicAdd(&bnsq[tid], s);
  }
}

// ---------------------------------------------------------------- BN finalize + ELU -> bf16
// each wave handles exactly one node (64 float4 = 256 channels). Optionally
// (gWp != null) also computes gate[n] = h.gW + gB and dec[n] = h.dW.
__global__ __launch_bounds__(256) void bn_elu_kernel(
    const float* __restrict__ Hb, const float* __restrict__ bnsum,
    const float* __restrict__ bnsq, const float* __restrict__ gma,
    const float* __restrict__ bta, __hip_bfloat16* __restrict__ H16,
    const float* __restrict__ gWp, const float* __restrict__ gBp,
    const float* __restrict__ dWp, float* __restrict__ gate,
    float* __restrict__ dec) {
  int idx = blockIdx.x * 256 + threadIdx.x;  // over kN*64 float4
  int d4 = idx & 63;
  int node = idx >> 6;
  float4 hv = ((const float4*)Hb)[idx];
  float4 s = ((const float4*)bnsum)[d4];
  float4 qq = ((const float4*)bnsq)[d4];
  float4 g = ((const float4*)gma)[d4];
  float4 b = ((const float4*)bta)[d4];
  const float inv_n = 1.f / (float)kN;
  auto f = [&](float h, float su, float sq, float ga, float be) {
    float mu = su * inv_n;
    float var = sq * inv_n - mu * mu;
    float y = ga * (h - mu) * rsqrtf(var + kEps) + be;
    return y > 0.f ? y : expm1f(y);
  };
  hv.x = f(hv.x, s.x, qq.x, g.x, b.x);
  hv.y = f(hv.y, s.y, qq.y, g.y, b.y);
  hv.z = f(hv.z, s.z, qq.z, g.z, b.z);
  hv.w = f(hv.w, s.w, qq.w, g.w, b.w);
  ushort4 rb;
  rb.x = f2bf(hv.x); rb.y = f2bf(hv.y); rb.z = f2bf(hv.z); rb.w = f2bf(hv.w);
  ((ushort4*)H16)[idx] = rb;
  if (gWp) {
    float4 gw = ((const float4*)gWp)[d4];
    float4 dw = ((const float4*)dWp)[d4];
    float tg = hv.x * gw.x + hv.y * gw.y + hv.z * gw.z + hv.w * gw.w;
    float td = hv.x * dw.x + hv.y * dw.y + hv.z * dw.z + hv.w * dw.w;
#pragma unroll
    for (int o = 32; o >= 1; o >>= 1) {
      tg += __shfl_xor(tg, o, 64);
      td += __shfl_xor(td, o, 64);
    }
    if (d4 == 0) {
      gate[node] = tg + gBp[0];
      dec[node] = td;
    }
  }
}

__device__ inline int lower_bound_dev(const int* a, int n, int key) {
  int lo = 0, hi = n;
  while (lo < hi) {
    int mid = (lo + hi) >> 1;
    if (a[mid] < key) lo = mid + 1; else hi = mid;
  }
  return lo;
}

// scalar segment-softmax pooling: out[g] = sum(a_n dec_n)/sum(a_n) + dB + oB
__global__ __launch_bounds__(256) void pool2_kernel(const float* __restrict__ gate,
                                                    const float* __restrict__ dec,
                                                    const int* __restrict__ batch,
                                                    const float* __restrict__ dB,
                                                    const float* __restrict__ oB,
                                                    float* __restrict__ out) {
  int g = blockIdx.x;
  int tid = threadIdx.x;
  int lane = tid & 63, w = tid >> 6;
  int lo = lower_bound_dev(batch, kN, g);
  int hi = lower_bound_dev(batch, kN, g + 1);
  float mx = -1e30f;
  for (int n = lo + tid; n < hi; n += 256) mx = fmaxf(mx, gate[n]);
#pragma unroll
  for (int o = 32; o >= 1; o >>= 1) mx = fmaxf(mx, __shfl_xor(mx, o, 64));
  __shared__ float sm[4];
  if (lane == 0) sm[w] = mx;
  __syncthreads();
  mx = fmaxf(fmaxf(sm[0], sm[1]), fmaxf(sm[2], sm[3]));
  float sn = 0.f, sd = 0.f;
  for (int n = lo + tid; n < hi; n += 256) {
    float a = __expf(gate[n] - mx);
    sn += a * dec[n];
    sd += a;
  }
#pragma unroll
  for (int o = 32; o >= 1; o >>= 1) {
    sn += __shfl_xor(sn, o, 64);
    sd += __shfl_xor(sd, o, 64);
  }
  __shared__ float s1[4], s2[4];
  if (lane == 0) { s1[w] = sn; s2[w] = sd; }
  __syncthreads();
  if (tid == 0) {
    float num = s1[0] + s1[1] + s1[2] + s1[3];
    float den = s2[0] + s2[1] + s2[2] + s2[3];
    out[g] = (den > 0.f ? num / den : 0.f) + dB[0] + oB[0];
  }
}

// ---------------------------------------------------------------- launch
extern "C" void kernel_launch(void* const* d_in, const int* in_sizes, int n_in,
                              void* d_out, int out_size, void* d_ws, size_t ws_size,
                              hipStream_t stream) {
  const float* x     = (const float*)d_in[0];
  const int*   ei    = (const int*)d_in[1];
  const float* eattr = (const float*)d_in[2];
  const int*   batch = (const int*)d_in[3];
  const float* encW  = (const float*)d_in[4];
  const float* encb  = (const float*)d_in[5];
  const float* Wq    = (const float*)d_in[6];
  const float* bq    = (const float*)d_in[7];
  const float* Wk    = (const float*)d_in[8];
  const float* bk    = (const float*)d_in[9];
  const float* Wv    = (const float*)d_in[10];
  const float* bv    = (const float*)d_in[11];
  const float* We    = (const float*)d_in[12];
  const float* Wsk   = (const float*)d_in[13];
  const float* bsk   = (const float*)d_in[14];
  const float* Wb    = (const float*)d_in[15];
  const float* bng   = (const float*)d_in[16];
  const float* bnb   = (const float*)d_in[17];
  const float* gW    = (const float*)d_in[18];
  const float* gB    = (const float*)d_in[19];
  const float* dW    = (const float*)d_in[20];
  const float* dB    = (const float*)d_in[21];
  const float* oB    = (const float*)d_in[22];
  float* out = (float*)d_out;

  char* base = (char*)d_ws;
  auto alloc = [&](size_t bytes) -> void* {
    void* p = (void*)base;
    base += (bytes + 255) & ~(size_t)255;
    return p;
  };
  float* hbuf   = (float*)alloc((size_t)kN * kD * 4);   // pre-BN h (fp32)
  float* qbuf   = (float*)alloc((size_t)kN * kD * 4);
  float* xrbuf  = (float*)alloc((size_t)kN * kD * 4);
  float* attbuf = (float*)alloc((size_t)kN * kD * 4);
  unsigned short* kvbuf = (unsigned short*)alloc((size_t)kN * 512 * 2);  // interleaved bf16 K|V
  __hip_bfloat16* h16 = (__hip_bfloat16*)alloc((size_t)kN * kD * 2);
  __hip_bfloat16* wt16 = (__hip_bfloat16*)alloc((size_t)8 * 65536 * 2);
  float* gatebuf = (float*)alloc((size_t)kN * 4);
  float* decbuf  = (float*)alloc((size_t)kN * 4);
  int* rowst  = (int*)alloc((size_t)(kN + 1) * 4);
  int* cursor = (int*)alloc((size_t)kN * 4);
  int* counts = (int*)alloc((size_t)kN * 4);
  int* perm   = (int*)alloc((size_t)kE * 4);
  float* bnsum = (float*)alloc(2048);  // 256 sum + 256 sumsq contiguous
  float* bnsq = bnsum + 256;

  // edge sort by dst
  hipMemsetAsync(counts, 0, (size_t)kN * 4, stream);
  hist_kernel<<<kE / 256, 256, 0, stream>>>(ei, counts);
  scan_kernel<<<1, 1024, 0, stream>>>(counts, rowst, cursor);
  scatter_kernel<<<kE / 256, 256, 0, stream>>>(ei, cursor, perm);

  // weights -> transposed bf16 (once)
  transpose_w_kernel<<<dim3(8, 8, 8), 256, 0, stream>>>(Wq, Wk, Wv, Wsk, wt16);

  // encoder (bf16 h)
  enc_kernel<<<kN * 64 / 256, 256, 0, stream>>>(x, encW, encb, h16);

  for (int l = 0; l < 2; ++l) {
    size_t bo = (size_t)l * kD;
    gemm4_mfma<<<dim3(8, kN / 128), 256, 0, stream>>>(
        h16, wt16 + (size_t)l * 4 * 65536,
        bq + bo, bk + bo, bv + bo, bsk + bo,
        qbuf, kvbuf, xrbuf);
    attn_kernel<<<kN / 4, 256, 0, stream>>>(qbuf, (const uint4*)kvbuf, eattr,
                                            We + bo, ei, perm, rowst, attbuf);
    hipMemsetAsync(bnsum, 0, 2048, stream);
    beta_bn_kernel<<<256, 256, 0, stream>>>(attbuf, xrbuf, Wb + (size_t)l * 768,
                                            hbuf, bnsum, bnsq);
    bool last = (l == 1);
    bn_elu_kernel<<<kN * 64 / 256, 256, 0, stream>>>(
        hbuf, bnsum, bnsq, bng + bo, bnb + bo, h16,
        last ? gW : nullptr, last ? gB : nullptr, last ? dW : nullptr,
        gatebuf, decbuf);
  }

  // readout
  pool2_kernel<<<kG, 256, 0, stream>>>(gatebuf, decbuf, batch, dB, oB, out);
}